// Round 7
// baseline (327.377 us; speedup 1.0000x reference)
//
#include <hip/hip_runtime.h>
#include <hip/hip_fp16.h>
#include <math.h>

#define CIN 128
#define C4  32
#define HW  12544      // 112*112
#define KNB 9
#define NWIN 392       // 8 * 7 * 7

__device__ inline double wave_sum(double v) {
#pragma unroll
    for (int off = 32; off; off >>= 1) v += __shfl_down(v, off);
    return v;
}

// predicated stable insert: strict '>' keeps earlier-inserted on ties (== lax.top_k)
#define TOP9_INSERT(sv, mi, tv, ti)                                  \
    {                                                                \
        _Pragma("unroll")                                            \
        for (int j = KNB - 1; j >= 1; --j) {                         \
            bool cj  = (sv) > tv[j];                                 \
            bool cjm = (sv) > tv[j - 1];                             \
            tv[j] = cj ? (cjm ? tv[j - 1] : (sv)) : tv[j];           \
            ti[j] = cj ? (cjm ? ti[j - 1] : (mi)) : ti[j];           \
        }                                                            \
        bool c0 = (sv) > tv[0];                                      \
        tv[0] = c0 ? (sv) : tv[0];                                   \
        ti[0] = c0 ? (mi) : ti[0];                                   \
    }

// ================= prep: weight transposes for scalar-load-friendly layouts =================
__global__ __launch_bounds__(256) void prep_kernel(
    const float* __restrict__ f_w, const float* __restrict__ r_w,
    const float* __restrict__ p_w,
    double* __restrict__ fw64t, float* __restrict__ rwt_t, float* __restrict__ pwt_t)
{
    const int i = blockIdx.x * 256 + threadIdx.x;
    if (i < 4096)  fw64t[(i & 127) * 32 + (i >> 7)]  = (double)f_w[i];  // [c][o], o<32
    if (i < 16384) rwt_t[(i & 127) * 128 + (i >> 7)] = r_w[i];          // [c][o], o<128
    if (i < 4096)  pwt_t[(i & 31) * 128 + (i >> 5)]  = p_w[i];          // [c][o], c<32
}

// ================= K1: fconv (blocks 0..391) + r-stats (blocks 392..1175) =================
__global__ __launch_bounds__(512, 6) void fconv_rstats_kernel(
    const float* __restrict__ x_in,
    const double* __restrict__ fw64t, const float* __restrict__ f_b,
    const float* __restrict__ f_gn_w, const float* __restrict__ f_gn_b,
    const float* __restrict__ rwt_t, const float* __restrict__ r_b,
    float* __restrict__ xfws, double* __restrict__ invnws,
    double* __restrict__ stats)
{
    __shared__ __align__(16) char smem[34944];
    double* vbuf = (double*)smem;               // [256][17] f64 exchange
    double* red  = (double*)(smem + 34816);     // [16]
    const int t = threadIdx.x;

    if (blockIdx.x < NWIN) {
        const int win = blockIdx.x;
        const int b = win / 49, wg = (win / 7) % 7, hg = win % 7;
        const int n = t & 255, s = t >> 8;
        const int py = n >> 4, px = n & 15;
        const int rs = __builtin_amdgcn_readfirstlane(s);

        const float* xb = x_in + (size_t)b * CIN * HW + (size_t)(wg * 16 + py) * 112 + (hg * 16 + px);
        const double* wB = fw64t + 16 * rs;     // wave-uniform base -> s_load weights
        double acc[16];
#pragma unroll
        for (int j = 0; j < 16; ++j) acc[j] = 0.0;
#pragma unroll 2
        for (int c = 0; c < CIN; ++c) {
            double xv = (double)xb[(size_t)c * HW];
            const double* wr = wB + c * 32;
#pragma unroll
            for (int j = 0; j < 16; ++j) acc[j] = fma(wr[j], xv, acc[j]);
        }
        double s1 = 0.0, s2 = 0.0;
#pragma unroll
        for (int j = 0; j < 16; ++j) {
            double v = acc[j] + (double)f_b[16 * rs + j];
            acc[j] = v; s1 += v; s2 += v * v;
        }
        s1 = wave_sum(s1); s2 = wave_sum(s2);
        {
            int w = t >> 6;
            if ((t & 63) == 0) { red[w] = s1; red[8 + w] = s2; }
        }
        __syncthreads();
        double rs1 = 0.0, rs2 = 0.0;
#pragma unroll
        for (int w = 0; w < 8; ++w) { rs1 += red[w]; rs2 += red[8 + w]; }
        const double mu   = rs1 * (1.0 / 8192.0);
        const double var  = rs2 * (1.0 / 8192.0) - mu * mu;
        const double rstd = 1.0 / sqrt(var + 1e-5);

        float myv[16];
#pragma unroll
        for (int j = 0; j < 16; ++j) {
            int c = 16 * rs + j;
            myv[j] = (float)((acc[j] - mu) * rstd * (double)f_gn_w[c] + (double)f_gn_b[c]);
        }
        float* xrow = xfws + (size_t)(win * 256 + n) * 36;
#pragma unroll
        for (int q4 = 0; q4 < 4; ++q4) {
            float4 f = { myv[4 * q4], myv[4 * q4 + 1], myv[4 * q4 + 2], myv[4 * q4 + 3] };
            ((float4*)(xrow + 16 * rs))[q4] = f;
        }
        const double ginv = 1.0 / (sqrt(5440.0 / 255.0) + 1e-5);   // 1/(grid std ddof=1 + eps)
        const float gyf = (float)(((double)py - 7.5) * ginv);
        const float gxf = (float)(((double)px - 7.5) * ginv);
        if (s == 0) {
            float4 g4 = { gyf, gxf, 0.f, 0.f };
            ((float4*)(xrow + 32))[0] = g4;
        }
        if (s == 1) {
#pragma unroll
            for (int j = 0; j < 16; ++j) vbuf[n * 17 + j] = (double)myv[j];
        }
        __syncthreads();
        if (s == 0) {
            double nrm = 0.0;
#pragma unroll
            for (int j = 0; j < 16; ++j) { double x = (double)myv[j]; nrm += x * x; }
#pragma unroll
            for (int j = 0; j < 16; ++j) { double x = vbuf[n * 17 + j]; nrm += x * x; }
            double xg = (double)gyf; nrm += xg * xg;
            double xh = (double)gxf; nrm += xh * xh;
            invnws[win * 256 + n] = 1.0 / fmax(sqrt(nrm), 1e-8);
        }
    } else {
        const int idx = blockIdx.x - NWIN;
        const int b = idx / 98, rem = idx % 98;
        const int oc = rem / 49, pg = rem % 49;
        const int sh = t >> 8, n = t & 255;
        const int rsh = __builtin_amdgcn_readfirstlane(sh);
        const float* wR = rwt_t + oc * 64 + rsh * 32;   // + c*128 per step, s_load
        const float* xb = x_in + (size_t)b * CIN * HW + pg * 256 + n;
        float acc[32];
#pragma unroll
        for (int o = 0; o < 32; ++o) acc[o] = r_b[oc * 64 + rsh * 32 + o];
#pragma unroll 2
        for (int c = 0; c < CIN; ++c) {
            float xv = xb[(size_t)c * HW];
            const float* wr = wR + c * 128;
#pragma unroll
            for (int o = 0; o < 32; ++o) acc[o] = fmaf(wr[o], xv, acc[o]);
        }
        double s1 = 0.0, s2 = 0.0;
#pragma unroll
        for (int o = 0; o < 32; ++o) { double v = (double)acc[o]; s1 += v; s2 += v * v; }
        s1 = wave_sum(s1); s2 = wave_sum(s2);
        {
            int w = t >> 6;
            if ((t & 63) == 0) { red[w] = s1; red[8 + w] = s2; }
        }
        __syncthreads();
        if (t == 0) {
            double a = 0.0, c = 0.0;
#pragma unroll
            for (int w = 0; w < 8; ++w) { a += red[w]; c += red[8 + w]; }
            atomicAdd(&stats[b * 4 + 0], a);
            atomicAdd(&stats[b * 4 + 1], c);
        }
    }
}

// ================= K2: sim (blocks 0..1567) + hm precompute (blocks 1568..2351) =================
__global__ __launch_bounds__(256, 4) void sim_hm_kernel(
    const float* __restrict__ xfws, const double* __restrict__ invnws,
    const float* __restrict__ e1_w,
    float* __restrict__ pval, unsigned char* __restrict__ pidx,
    __half* __restrict__ hmws)
{
    const int bid = blockIdx.x;
    if (bid < 4 * NWIN) {
        // ---- sim + partial top-9 (fp64 path, unchanged arithmetic) ----
        const int win = bid >> 2, m0 = (bid & 3) << 6;
        const int n = threadIdx.x;

        double xad[34];
        {
            const float4* own = (const float4*)(xfws + (size_t)(win * 256 + n) * 36);
#pragma unroll
            for (int q = 0; q < 8; ++q) {
                float4 f = own[q];
                xad[q * 4 + 0] = (double)f.x; xad[q * 4 + 1] = (double)f.y;
                xad[q * 4 + 2] = (double)f.z; xad[q * 4 + 3] = (double)f.w;
            }
            float4 g = own[8];
            xad[32] = (double)g.x; xad[33] = (double)g.y;
        }
        const double inv_self = invnws[(size_t)win * 256 + n];
        const float*  xmb  = xfws + (size_t)(win * 256 + m0) * 36;   // block-uniform rows
        const double* invb = invnws + (size_t)win * 256 + m0;

        float tv[KNB]; int ti[KNB];
#pragma unroll
        for (int k = 0; k < KNB; ++k) { tv[k] = -INFINITY; ti[k] = 0; }
#pragma unroll 2
        for (int mm = 0; mm < 64; ++mm) {
            const float* xm = xmb + mm * 36;     // uniform -> s_load batches
            double d0 = 0.0, d1 = 0.0, d2 = 0.0, d3 = 0.0;
#pragma unroll
            for (int q = 0; q < 8; ++q) {
                d0 = fma((double)xm[4 * q + 0], xad[4 * q + 0], d0);
                d1 = fma((double)xm[4 * q + 1], xad[4 * q + 1], d1);
                d2 = fma((double)xm[4 * q + 2], xad[4 * q + 2], d2);
                d3 = fma((double)xm[4 * q + 3], xad[4 * q + 3], d3);
            }
            d0 = fma((double)xm[32], xad[32], d0);
            d1 = fma((double)xm[33], xad[33], d1);
            double d = (d0 + d1) + (d2 + d3);
            float sv = (float)(d * (inv_self * invb[mm]));
            sv = (m0 + mm == n) ? -INFINITY : sv;
            TOP9_INSERT(sv, m0 + mm, tv, ti);
        }
        const size_t base = ((size_t)bid * 256 + n) * 9;
#pragma unroll
        for (int k = 0; k < KNB; ++k) { pval[base + k] = tv[k]; pidx[base + k] = (unsigned char)ti[k]; }
    } else {
        // ---- hm: per node, 16 msg-half hidden units; weights via s_load ----
        const int idxm = bid - 4 * NWIN;
        const int win = idxm >> 1, half = idxm & 1;
        const int t = threadIdx.x;
        const int n = t & 127;
        const int jh = __builtin_amdgcn_readfirstlane(t >> 7);
        const int gn = half * 128 + n;
        const float4* xr4 = (const float4*)(xfws + (size_t)(win * 256 + gn) * 36);
        float xr[32];
#pragma unroll
        for (int q = 0; q < 8; ++q) {
            float4 f = xr4[q];
            xr[4 * q + 0] = f.x; xr[4 * q + 1] = f.y;
            xr[4 * q + 2] = f.z; xr[4 * q + 3] = f.w;
        }
        __align__(16) __half hv[16];
#pragma unroll
        for (int jj = 0; jj < 16; ++jj) {
            const float* w = e1_w + (16 * jh + jj) * 64 + 32;
            float a = 0.f;
#pragma unroll
            for (int c = 0; c < C4; ++c) a = fmaf(w[c], xr[c], a);
            hv[jj] = __float2half_rn(a);
        }
        float4* dst = (float4*)(hmws + (size_t)(win * 256 + gn) * 32 + 16 * jh);
        dst[0] = ((const float4*)hv)[0];
        dst[1] = ((const float4*)hv)[1];
    }
}

// ================= K3: merge + edges + aggregate (fp16 LDS, 3 blocks/CU) =================
// block = (window, node-half); 512 threads = (nl in [0,128), s in [0,4))
// LDS 50432 B: xf2[256][17]h2 | hm2[256][17]h2 | hs2[128][17]h2 | Ti[1152]i16 | Wt[1152]f32
__global__ __launch_bounds__(512, 6) void merge_mlp_kernel(
    const float* __restrict__ xfws, const __half* __restrict__ hmws,
    const float* __restrict__ pval, const unsigned char* __restrict__ pidx,
    const float* __restrict__ e1_w, const float* __restrict__ e1_b,
    const float* __restrict__ e2_w, const float* __restrict__ e2_b,
    const float* __restrict__ gamma, const float* __restrict__ beta,
    float* __restrict__ gnn)
{
    __shared__ __align__(16) char smem[50432];
    __half2* xf2 = (__half2*)smem;              // [256][17]
    __half2* hm2 = (__half2*)(smem + 17408);    // [256][17]
    __half2* hs2 = (__half2*)(smem + 34816);    // [128][17]
    short*   Ti  = (short*)(smem + 43520);
    float*   Wt  = (float*)(smem + 45824);

    const int bid = blockIdx.x;
    const int win = bid >> 1, half = bid & 1;
    const int b = win / 49, wg = (win / 7) % 7, hg = win % 7;
    const int t = threadIdx.x;
    const int nl = t & 127, s = t >> 7;
    const int gn = half * 128 + nl;
    const int rs = __builtin_amdgcn_readfirstlane(s);

    // stage: xf (f32->fp16) + hm (fp16 bit-copy)
    {
        const int r = t >> 1, hh = t & 1;
        const float4* sx = (const float4*)(xfws + (size_t)win * 9216 + r * 36 + hh * 16);
#pragma unroll
        for (int q = 0; q < 4; ++q) {
            float4 f = sx[q];
            xf2[r * 17 + hh * 8 + 2 * q]     = __floats2half2_rn(f.x, f.y);
            xf2[r * 17 + hh * 8 + 2 * q + 1] = __floats2half2_rn(f.z, f.w);
        }
        const uint4* sh = (const uint4*)(hmws + (size_t)win * 8192 + r * 32 + hh * 16);
        uint4 u0 = sh[0], u1 = sh[1];
        unsigned int* d = (unsigned int*)(hm2 + r * 17 + hh * 8);
        d[0] = u0.x; d[1] = u0.y; d[2] = u0.z; d[3] = u0.w;
        d[4] = u1.x; d[5] = u1.y; d[6] = u1.z; d[7] = u1.w;
    }
    __syncthreads();

    // hs (all threads, 8 units each) -> hs2
    {
        float xr[C4];
#pragma unroll
        for (int q = 0; q < 16; ++q) {
            float2 f = __half22float2(xf2[gn * 17 + q]);
            xr[2 * q] = f.x; xr[2 * q + 1] = f.y;
        }
        float hsv[8];
#pragma unroll
        for (int jj = 0; jj < 8; ++jj) {
            const int j = 8 * rs + jj;
            const float* w = e1_w + j * 64;
            float h0 = e1_b[j], h1 = 0.f;
#pragma unroll
            for (int c = 0; c < C4; c += 2) {
                h0 = fmaf(w[c], xr[c], h0);
                h1 = fmaf(w[c + 1], xr[c + 1], h1);
            }
            hsv[jj] = h0 + h1;
        }
#pragma unroll
        for (int u = 0; u < 4; ++u)
            hs2[nl * 17 + 4 * rs + u] = __floats2half2_rn(hsv[2 * u], hsv[2 * u + 1]);
    }
    // merge 4 quarter lists (s==0; ascending qd == ascending m => stable == lax.top_k)
    if (s == 0) {
        float tv[KNB]; int ti[KNB];
#pragma unroll
        for (int k = 0; k < KNB; ++k) { tv[k] = -INFINITY; ti[k] = 0; }
        for (int qd = 0; qd < 4; ++qd) {
            const size_t base = ((size_t)(win * 4 + qd) * 256 + gn) * 9;
#pragma unroll
            for (int k = 0; k < KNB; ++k) {
                float sv = pval[base + k];
                int   mi = (int)pidx[base + k];
                TOP9_INSERT(sv, mi, tv, ti);
            }
        }
#pragma unroll
        for (int k = 0; k < KNB; ++k) Ti[nl * 9 + k] = (short)ti[k];
    }
    __syncthreads();

    // edges: wgt = sigmoid(e2 . silu(hs[n] + hm[m]) + e2b); k in {s, s+4, s+8}
    {
        float hsr[C4];
#pragma unroll
        for (int q = 0; q < 16; ++q) {
            float2 f = __half22float2(hs2[nl * 17 + q]);
            hsr[2 * q] = f.x; hsr[2 * q + 1] = f.y;
        }
        const float e2b = e2_b[0];
        for (int k = s; k < KNB; k += 4) {
            const int m = (int)Ti[nl * 9 + k];
            float a2 = 0.f;
#pragma unroll
            for (int jp = 0; jp < 16; ++jp) {
                float2 hv = __half22float2(hm2[m * 17 + jp]);
                float h0 = hsr[2 * jp] + hv.x;
                float h1 = hsr[2 * jp + 1] + hv.y;
                float sg0 = 1.f / (1.f + __expf(-h0));
                a2 = fmaf(e2_w[2 * jp], h0 * sg0, a2);
                float sg1 = 1.f / (1.f + __expf(-h1));
                a2 = fmaf(e2_w[2 * jp + 1], h1 * sg1, a2);
            }
            Wt[nl * 9 + k] = 1.f / (1.f + __expf(-(a2 + e2b)));
        }
    }
    __syncthreads();

    // aggregate: thread (nl,s) channels [8rs,8rs+8); write gnn
    {
        short tis[KNB]; float wks[KNB];
#pragma unroll
        for (int k = 0; k < KNB; ++k) { tis[k] = Ti[nl * 9 + k]; wks[k] = Wt[nl * 9 + k]; }
        const float g = gamma[0], be = beta[0];
        const int py = gn >> 4, px = gn & 15;
        float* gp = gnn + (size_t)b * C4 * HW + (size_t)(wg * 16 + py) * 112 + (hg * 16 + px);
        float xo[8];
#pragma unroll
        for (int q = 0; q < 4; ++q) {
            float2 f = __half22float2(xf2[gn * 17 + 4 * rs + q]);
            xo[2 * q] = f.x; xo[2 * q + 1] = f.y;
        }
        float o[8];
#pragma unroll
        for (int cc = 0; cc < 8; ++cc) o[cc] = 0.f;
#pragma unroll
        for (int k = 0; k < KNB; ++k) {
            const int mrow = (int)tis[k] * 17 + 4 * rs;
#pragma unroll
            for (int q = 0; q < 4; ++q) {
                float2 mv = __half22float2(xf2[mrow + q]);
                o[2 * q]     = fmaf(wks[k], mv.x, o[2 * q]);
                o[2 * q + 1] = fmaf(wks[k], mv.y, o[2 * q + 1]);
            }
        }
#pragma unroll
        for (int cc = 0; cc < 8; ++cc) {
            float gl = fmaf(g, o[cc], be * xo[cc]);
            gp[(size_t)(8 * rs + cc) * HW] = gl;
        }
    }
}

// ================= K4: p-stats from gnn; zero LDS (bar tiny reduce), scalar weights =================
__global__ __launch_bounds__(256, 8) void pstats_kernel(
    const float* __restrict__ gnn, const float* __restrict__ p_w,
    const float* __restrict__ p_b, double* __restrict__ stats)
{
    __shared__ double red[16];
    const int idx = blockIdx.x;
    const int b = idx / 98, pg = idx % 98;
    const int t = threadIdx.x;
    const int pix = pg * 128 + (t & 127);
    const int oh = __builtin_amdgcn_readfirstlane(t >> 7);   // wave-uniform out-half

    const float* gb = gnn + (size_t)b * C4 * HW + pix;
    float g[C4];
#pragma unroll
    for (int c = 0; c < C4; ++c) g[c] = gb[(size_t)c * HW];

    double s1 = 0.0, s2 = 0.0;
    const float* pwb = p_w + (size_t)oh * 64 * C4;
#pragma unroll 4
    for (int o = 0; o < 64; ++o) {
        const float* w = pwb + o * C4;
        float y = p_b[oh * 64 + o];
#pragma unroll
        for (int c = 0; c < C4; ++c) y = fmaf(w[c], g[c], y);
        s1 += (double)y; s2 += (double)y * (double)y;
    }
    s1 = wave_sum(s1); s2 = wave_sum(s2);
    {
        int w = t >> 6;
        if ((t & 63) == 0) { red[w] = s1; red[8 + w] = s2; }
    }
    __syncthreads();
    if (t == 0) {
        double a = 0.0, c = 0.0;
#pragma unroll
        for (int w = 0; w < 4; ++w) { a += red[w]; c += red[8 + w]; }
        atomicAdd(&stats[b * 4 + 2], a);
        atomicAdd(&stats[b * 4 + 3], c);
    }
}

// ================= final: GN(r)+GN(p)+add; zero LDS, weights via scalar =================
__global__ __launch_bounds__(256) void final_kernel(
    const float* __restrict__ x_in, const float* __restrict__ gnn,
    const float* __restrict__ rwt_t, const float* __restrict__ r_b,
    const float* __restrict__ r_gn_w, const float* __restrict__ r_gn_b,
    const float* __restrict__ pwt_t, const float* __restrict__ p_b,
    const float* __restrict__ p_gn_w, const float* __restrict__ p_gn_b,
    const double* __restrict__ stats,
    float* __restrict__ out)
{
    const int idx = blockIdx.x;
    const int b = idx / 196, rem = idx % 196;
    const int ocq = rem / 49, pg = rem % 49;
    const int t = threadIdx.x;

    const double NN = (double)CIN * HW;
    const double mu_r = stats[b * 4 + 0] / NN;
    const float  rs_r = (float)(1.0 / sqrt(stats[b * 4 + 1] / NN - mu_r * mu_r + 1e-5));
    const double mu_p = stats[b * 4 + 2] / NN;
    const float  rs_p = (float)(1.0 / sqrt(stats[b * 4 + 3] / NN - mu_p * mu_p + 1e-5));
    const float fmur = (float)mu_r, fmup = (float)mu_p;

    const int p = pg * 256 + t;
    const float* xb = x_in + (size_t)b * CIN * HW + p;
    const float* gb = gnn + (size_t)b * C4 * HW + p;
    float* ob = out + (size_t)b * CIN * HW + p;

    float xg[C4];
#pragma unroll
    for (int c = 0; c < C4; ++c) xg[c] = gb[(size_t)c * HW];

    float accR[32], accP[32];
#pragma unroll
    for (int o = 0; o < 32; ++o) {
        accR[o] = r_b[ocq * 32 + o];
        accP[o] = p_b[ocq * 32 + o];
    }
#pragma unroll 2
    for (int c = 0; c < CIN; ++c) {
        float xv = xb[(size_t)c * HW];
        const float* w = rwt_t + c * 128 + ocq * 32;
#pragma unroll
        for (int o = 0; o < 32; ++o) accR[o] = fmaf(w[o], xv, accR[o]);
    }
#pragma unroll
    for (int c = 0; c < C4; ++c) {
        const float* w = pwt_t + c * 128 + ocq * 32;
#pragma unroll
        for (int o = 0; o < 32; ++o) accP[o] = fmaf(w[o], xg[c], accP[o]);
    }
#pragma unroll
    for (int o = 0; o < 32; ++o) {
        const int O = ocq * 32 + o;
        float yr = (accR[o] - fmur) * rs_r * r_gn_w[O] + r_gn_b[O];
        float yp = (accP[o] - fmup) * rs_p * p_gn_w[O] + p_gn_b[O];
        ob[(size_t)O * HW] = yp + yr;
    }
}

extern "C" void kernel_launch(void* const* d_in, const int* in_sizes, int n_in,
                              void* d_out, int out_size, void* d_ws, size_t ws_size,
                              hipStream_t stream)
{
    const float* x_in   = (const float*)d_in[0];
    const float* f_w    = (const float*)d_in[1];
    const float* f_b    = (const float*)d_in[2];
    const float* f_gn_w = (const float*)d_in[3];
    const float* f_gn_b = (const float*)d_in[4];
    const float* p_w    = (const float*)d_in[5];
    const float* p_b    = (const float*)d_in[6];
    const float* p_gn_w = (const float*)d_in[7];
    const float* p_gn_b = (const float*)d_in[8];
    const float* r_w    = (const float*)d_in[9];
    const float* r_b    = (const float*)d_in[10];
    const float* r_gn_w = (const float*)d_in[11];
    const float* r_gn_b = (const float*)d_in[12];
    const float* e1_w   = (const float*)d_in[13];
    const float* e1_b   = (const float*)d_in[14];
    const float* e2_w   = (const float*)d_in[15];
    const float* e2_b   = (const float*)d_in[16];
    const float* gamma  = (const float*)d_in[17];
    const float* beta   = (const float*)d_in[18];

    char* wsb = (char*)d_ws;
    float*         gnn    = (float*)        (wsb + 0);          // 12,845,056
    double*        stats  = (double*)       (wsb + 12845056);   // 256
    float*         xfws   = (float*)        (wsb + 12845312);   // 14,450,688
    double*        invnws = (double*)       (wsb + 27296000);   // 802,816
    float*         pval   = (float*)        (wsb + 28098816);   // 14,450,688
    unsigned char* pidx   = (unsigned char*)(wsb + 42549504);   // 3,612,672
    double*        fw64t  = (double*)       (wsb + 46162176);   // 32,768
    float*         rwt_t  = (float*)        (wsb + 46194944);   // 65,536
    float*         pwt_t  = (float*)        (wsb + 46260480);   // 16,384
    __half*        hmws   = (__half*)       (wsb + 46276864);   // 6,422,528 (end ~52.7 MB)

    hipMemsetAsync(stats, 0, 32 * sizeof(double), stream);
    prep_kernel<<<64, 256, 0, stream>>>(f_w, r_w, p_w, fw64t, rwt_t, pwt_t);
    fconv_rstats_kernel<<<NWIN + 784, 512, 0, stream>>>(
        x_in, fw64t, f_b, f_gn_w, f_gn_b, rwt_t, r_b, xfws, invnws, stats);
    sim_hm_kernel<<<NWIN * 4 + NWIN * 2, 256, 0, stream>>>(
        xfws, invnws, e1_w, pval, pidx, hmws);
    merge_mlp_kernel<<<NWIN * 2, 512, 0, stream>>>(
        xfws, hmws, pval, pidx, e1_w, e1_b, e2_w, e2_b, gamma, beta, gnn);
    pstats_kernel<<<784, 256, 0, stream>>>(gnn, p_w, p_b, stats);
    final_kernel<<<1568, 256, 0, stream>>>(
        x_in, gnn, rwt_t, r_b, r_gn_w, r_gn_b, pwt_t, p_b, p_gn_w, p_gn_b, stats, (float*)d_out);
}